// Round 1
// baseline (477.711 us; speedup 1.0000x reference)
//
#include <hip/hip_runtime.h>
#include <math.h>

#define BB 4
#define CC 128
#define HH 128
#define WW 128
#define OO 256
#define HWP 16384   // H*W

// ---------------------------------------------------------------------------
// P1: NCHW -> NHWC transpose of x (into d_out's first half, used as scratch).
// Per (b,h): 128x128 (c,w) transpose via 64x64 LDS tiles, +1 pad.
// ---------------------------------------------------------------------------
__global__ __launch_bounds__(256) void k_transpose(const float* __restrict__ x,
                                                   float* __restrict__ xn) {
  __shared__ float tile[64][65];
  int wt = blockIdx.x & 1;
  int ct = blockIdx.x >> 1;
  int h = blockIdx.y, b = blockIdx.z;
  int tw = threadIdx.x & 63;
  int tc = threadIdx.x >> 6;
#pragma unroll
  for (int i = 0; i < 16; i++) {
    int c = ct * 64 + i * 4 + tc;
    tile[i * 4 + tc][tw] = x[((b * CC + c) * HH + h) * WW + wt * 64 + tw];
  }
  __syncthreads();
#pragma unroll
  for (int i = 0; i < 16; i++) {
    int w = wt * 64 + i * 4 + tc;
    xn[((b * HH + h) * WW + w) * CC + ct * 64 + tw] = tile[tw][i * 4 + tc];
  }
}

// ---------------------------------------------------------------------------
// P2: offset conv: om[b][o][h][w], o in [0,27). Thread = one pixel, acc[27].
// Weights w_off[o][c][t] are wave-uniform -> compiler scalarizes (s_load),
// so inner loop is 27 FMA per (c,tap) with 1 vector load per tap.
// ---------------------------------------------------------------------------
__global__ __launch_bounds__(128) void k_offconv(const float* __restrict__ x,
                                                 const float* __restrict__ w_off,
                                                 const float* __restrict__ b_off,
                                                 float* __restrict__ om) {
  int w = threadIdx.x;   // 0..127
  int h = blockIdx.x;    // 0..127
  int b = blockIdx.y;    // 0..3
  float acc[27];
#pragma unroll
  for (int o = 0; o < 27; o++) acc[o] = b_off[o];
  for (int c = 0; c < CC; c++) {
    const float* xr = x + ((b * CC + c) * HH) * WW;
    float xv[9];
#pragma unroll
    for (int t = 0; t < 9; t++) {
      int yy = h + t / 3 - 1;
      int xx = w + t % 3 - 1;
      bool ok = (yy >= 0) && (yy < HH) && (xx >= 0) && (xx < WW);
      xv[t] = ok ? xr[yy * WW + xx] : 0.0f;
    }
    const float* wo = w_off + c * 9;  // w_off[(o*CC + c)*9 + t]
#pragma unroll
    for (int o = 0; o < 27; o++) {
      const float* wp = wo + o * CC * 9;
#pragma unroll
      for (int t = 0; t < 9; t++) acc[o] = fmaf(wp[t], xv[t], acc[o]);
    }
  }
  int base = b * 27 * HWP + h * WW + w;
#pragma unroll
  for (int o = 0; o < 27; o++) om[base + o * HWP] = acc[o];
}

// ---------------------------------------------------------------------------
// P3: deformable bilinear sampling + mask + depthwise -> out1[b][h][w][c].
// Block = 4 pixels (4 waves). Phase 1: 36 threads compute per-(pixel,k)
// sampling params (clamped base addr, row/col steps, 4 mask-folded weights)
// into LDS. Phase 2: wave = pixel, lane = 2 channels; 4 contiguous float2
// corner loads per tap from NHWC x.
// ---------------------------------------------------------------------------
__global__ __launch_bounds__(256) void k_sample(const float* __restrict__ xn,
                                                const float* __restrict__ om,
                                                const float* __restrict__ w_dw,
                                                const float* __restrict__ b_dw,
                                                float* __restrict__ out1) {
  __shared__ int s_base[4][9], s_dxs[4][9], s_dys[4][9];
  __shared__ float s_w[4][9][4];
  int tid = threadIdx.x;
  int n0 = blockIdx.x * 4;
  if (tid < 36) {
    int pix = tid / 9, k = tid - pix * 9;
    int n = n0 + pix;
    int b = n >> 14, rem = n & 16383;
    int h = rem >> 7, w = rem & 127;
    const float* op = om + b * 27 * HWP + rem;
    float dy = op[(2 * k) * HWP];
    float dx = op[(2 * k + 1) * HWP];
    float mv = op[(18 + k) * HWP];
    mv = 1.0f / (1.0f + __expf(-mv));
    float py = (float)(h + k / 3 - 1) + dy;
    float px = (float)(w + k % 3 - 1) + dx;
    float y0f = floorf(py), x0f = floorf(px);
    float wy = py - y0f, wx = px - x0f;
    int y0 = (int)y0f, x0 = (int)x0f;
    int y1 = y0 + 1, x1 = x0 + 1;
    float v00 = (y0 >= 0 && y0 < HH && x0 >= 0 && x0 < WW) ? 1.f : 0.f;
    float v01 = (y0 >= 0 && y0 < HH && x1 >= 0 && x1 < WW) ? 1.f : 0.f;
    float v10 = (y1 >= 0 && y1 < HH && x0 >= 0 && x0 < WW) ? 1.f : 0.f;
    float v11 = (y1 >= 0 && y1 < HH && x1 >= 0 && x1 < WW) ? 1.f : 0.f;
    int y0c = min(max(y0, 0), HH - 1), y1c = min(max(y1, 0), HH - 1);
    int x0c = min(max(x0, 0), WW - 1), x1c = min(max(x1, 0), WW - 1);
    s_base[pix][k] = ((b * HH + y0c) * WW + x0c) * CC;
    s_dxs[pix][k] = (x1c - x0c) * CC;
    s_dys[pix][k] = (y1c - y0c) * WW * CC;
    s_w[pix][k][0] = (1.f - wy) * (1.f - wx) * mv * v00;
    s_w[pix][k][1] = (1.f - wy) * wx * mv * v01;
    s_w[pix][k][2] = wy * (1.f - wx) * mv * v10;
    s_w[pix][k][3] = wy * wx * mv * v11;
  }
  __syncthreads();
  int wv = tid >> 6, lane = tid & 63;
  int n = n0 + wv;
  int c0 = lane * 2;
  float wka[9], wkb[9];
#pragma unroll
  for (int k = 0; k < 9; k++) {
    wka[k] = w_dw[c0 * 9 + k];        // w_dw[c][k], c = c0
    wkb[k] = w_dw[c0 * 9 + 9 + k];    // c = c0+1
  }
  float ax = 0.f, ay = 0.f;
#pragma unroll
  for (int k = 0; k < 9; k++) {
    int base = s_base[wv][k] + c0;
    int dxs = s_dxs[wv][k], dys = s_dys[wv][k];
    float4 wgt = *(const float4*)s_w[wv][k];
    float2 v00 = *(const float2*)(xn + base);
    float2 v01 = *(const float2*)(xn + base + dxs);
    float2 v10 = *(const float2*)(xn + base + dys);
    float2 v11 = *(const float2*)(xn + base + dys + dxs);
    float sx = v00.x * wgt.x + v01.x * wgt.y + v10.x * wgt.z + v11.x * wgt.w;
    float sy = v00.y * wgt.x + v01.y * wgt.y + v10.y * wgt.z + v11.y * wgt.w;
    ax = fmaf(sx, wka[k], ax);
    ay = fmaf(sy, wkb[k], ay);
  }
  ax += b_dw[c0];
  ay += b_dw[c0 + 1];
  *(float2*)(out1 + n * CC + c0) = make_float2(ax, ay);
}

// ---------------------------------------------------------------------------
// P4: pointwise GEMM: out[b][o][hw] = sum_c out1[n][c] * w_pw[o][c] + b_pw.
// Block tile 128(o) x 128(n), 256 threads, 8x8 per thread, k-chunks of 32,
// k-major LDS tiles (stride 132 for alignment + conflict spread).
// ---------------------------------------------------------------------------
__global__ __launch_bounds__(256) void k_pw(const float* __restrict__ wpw,
                                            const float* __restrict__ bpw,
                                            const float* __restrict__ bmat,
                                            float* __restrict__ out) {
  __shared__ float As[32][132];
  __shared__ float Bs[32][132];
  int o0 = blockIdx.x * 128;
  int n0 = blockIdx.y * 128;
  int tid = threadIdx.x;
  int to = tid >> 4, tn = tid & 15;
  float acc[8][8] = {};
  for (int kc = 0; kc < 128; kc += 32) {
    __syncthreads();
#pragma unroll
    for (int i = 0; i < 16; i++) {
      int e = i * 256 + tid;
      int oo = e >> 5, kk = e & 31;
      As[kk][oo] = wpw[(o0 + oo) * CC + kc + kk];
    }
#pragma unroll
    for (int i = 0; i < 16; i++) {
      int e = i * 256 + tid;
      int nn = e >> 5, kk = e & 31;
      Bs[kk][nn] = bmat[(n0 + nn) * CC + kc + kk];
    }
    __syncthreads();
#pragma unroll
    for (int kk = 0; kk < 32; kk++) {
      float av[8], bv[8];
#pragma unroll
      for (int i = 0; i < 8; i++) av[i] = As[kk][to * 8 + i];
#pragma unroll
      for (int j = 0; j < 8; j++) bv[j] = Bs[kk][tn * 8 + j];
#pragma unroll
      for (int i = 0; i < 8; i++)
#pragma unroll
        for (int j = 0; j < 8; j++) acc[i][j] = fmaf(av[i], bv[j], acc[i][j]);
    }
  }
#pragma unroll
  for (int i = 0; i < 8; i++) {
    int o = o0 + to * 8 + i;
    float bo = bpw[o];
#pragma unroll
    for (int j = 0; j < 8; j++) {
      int n = n0 + tn * 8 + j;
      int b = n >> 14, hw = n & 16383;
      out[(b * OO + o) * HWP + hw] = acc[i][j] + bo;
    }
  }
}

// ---------------------------------------------------------------------------
extern "C" void kernel_launch(void* const* d_in, const int* in_sizes, int n_in,
                              void* d_out, int out_size, void* d_ws, size_t ws_size,
                              hipStream_t stream) {
  const float* x     = (const float*)d_in[0];
  const float* w_off = (const float*)d_in[1];
  const float* b_off = (const float*)d_in[2];
  const float* w_dw  = (const float*)d_in[3];
  const float* b_dw  = (const float*)d_in[4];
  const float* w_pw  = (const float*)d_in[5];
  const float* b_pw  = (const float*)d_in[6];
  float* out = (float*)d_out;
  float* ws  = (float*)d_ws;

  // scratch layout
  float* xn   = out;            // 8388608 floats in d_out[0..] (consumed before P4 overwrites)
  float* om   = ws;             // 1769472 floats
  float* out1 = ws + 1769472;   // 8388608 floats  (total ws use ~40.6 MB)

  k_transpose<<<dim3(4, 128, 4), 256, 0, stream>>>(x, xn);
  k_offconv<<<dim3(128, 4), 128, 0, stream>>>(x, w_off, b_off, om);
  k_sample<<<16384, 256, 0, stream>>>(xn, om, w_dw, b_dw, out1);
  k_pw<<<dim3(2, 512), 256, 0, stream>>>(w_pw, b_pw, out1, out);
}

// Round 2
// 311.569 us; speedup vs baseline: 1.5332x; 1.5332x over previous
//
#include <hip/hip_runtime.h>
#include <hip/hip_bf16.h>
#include <math.h>

#define BB 4
#define CC 128
#define HH 128
#define WW 128
#define OO 256
#define HWP 16384   // H*W

typedef __attribute__((ext_vector_type(8))) short short8;   // bf16x8 MFMA frag
typedef __attribute__((ext_vector_type(4))) float floatx4;  // MFMA C/D frag

// ---------------------------------------------------------------------------
// P1: NCHW -> NHWC transpose of x; emits fp32 xn + bf16 hi/lo copies (xh, xl).
// ---------------------------------------------------------------------------
__global__ __launch_bounds__(256) void k_transpose(const float* __restrict__ x,
                                                   float* __restrict__ xn,
                                                   __hip_bfloat16* __restrict__ xh,
                                                   __hip_bfloat16* __restrict__ xl) {
  __shared__ float tile[64][65];
  int wt = blockIdx.x & 1;
  int ct = blockIdx.x >> 1;
  int h = blockIdx.y, b = blockIdx.z;
  int tw = threadIdx.x & 63;
  int tc = threadIdx.x >> 6;
#pragma unroll
  for (int i = 0; i < 16; i++) {
    int c = ct * 64 + i * 4 + tc;
    tile[i * 4 + tc][tw] = x[((b * CC + c) * HH + h) * WW + wt * 64 + tw];
  }
  __syncthreads();
#pragma unroll
  for (int i = 0; i < 16; i++) {
    int w = wt * 64 + i * 4 + tc;
    int idx = ((b * HH + h) * WW + w) * CC + ct * 64 + tw;
    float v = tile[tw][i * 4 + tc];
    __hip_bfloat16 hv = __float2bfloat16(v);
    float rv = __bfloat162float(hv);
    xn[idx] = v;
    xh[idx] = hv;
    xl[idx] = __float2bfloat16(v - rv);
  }
}

// ---------------------------------------------------------------------------
// P1b: weight prep for MFMA offconv. K-index k = t*128 + c (t=tap, c=channel).
// Layout Ahi/Alo[k>>3][o(32)][k&7] bf16 so A-frag loads are lane-contiguous.
// o in [27,32) zero-padded.
// ---------------------------------------------------------------------------
__global__ __launch_bounds__(256) void k_wprep(const float* __restrict__ w_off,
                                               __hip_bfloat16* __restrict__ Ahi,
                                               __hip_bfloat16* __restrict__ Alo) {
  int e = blockIdx.x * 256 + threadIdx.x;   // [144][32][8] = 36864
  if (e >= 144 * 32 * 8) return;
  int kblk = e >> 8;
  int o = (e >> 3) & 31;
  int j = e & 7;
  int k = kblk * 8 + j;
  int t = k >> 7, c = k & 127;
  float w = (o < 27) ? w_off[(o * CC + c) * 9 + t] : 0.0f;
  __hip_bfloat16 hv = __float2bfloat16(w);
  Ahi[e] = hv;
  Alo[e] = __float2bfloat16(w - __bfloat162float(hv));
}

// ---------------------------------------------------------------------------
// P2: offset conv as MFMA implicit GEMM.
// om[27 x 65536] = (Whi+Wlo)[27x1152] . (xh+xl)[1152x65536], dropping lo.lo.
// Block = 256 thr = 4 waves = one image row (128 w). Wave: 32 pixels x 32 o.
// Per K-step (32 k): 8 x 16B loads + 12 MFMA (16x16x32 bf16).
// ---------------------------------------------------------------------------
__global__ __launch_bounds__(256) void k_offconv_mfma(
    const __hip_bfloat16* __restrict__ xh, const __hip_bfloat16* __restrict__ xl,
    const __hip_bfloat16* __restrict__ Ahi, const __hip_bfloat16* __restrict__ Alo,
    const float* __restrict__ b_off, float* __restrict__ om) {
  int tid = threadIdx.x;
  int wv = tid >> 6, lane = tid & 63;
  int h = blockIdx.x, b = blockIdx.y;
  int w0 = wv * 32;
  int n16 = lane & 15, quad = lane >> 4;

  floatx4 acc[2][2] = {};   // Whi·xh + Whi·xl   [m-tile][n-frag]
  floatx4 acc2[2][2] = {};  // Wlo·xh
  short8 zz = {};

  for (int t = 0; t < 9; t++) {
    int dy = t / 3 - 1, dx = t % 3 - 1;
    int hs = h + dy;
    bool hok = ((unsigned)hs < HH);
    int hsc = min(max(hs, 0), HH - 1);
    int wA = w0 + n16 + dx;
    int wB = wA + 16;
    bool okA = hok && ((unsigned)wA < WW);
    bool okB = hok && ((unsigned)wB < WW);
    int wAc = min(max(wA, 0), WW - 1);
    int wBc = min(max(wB, 0), WW - 1);
    size_t offA = (size_t)((b * HH + hsc) * WW + wAc) * CC + quad * 8;
    size_t offB = (size_t)((b * HH + hsc) * WW + wBc) * CC + quad * 8;
#pragma unroll
    for (int cs = 0; cs < 4; cs++) {
      int co = cs * 32;
      short8 bhA = *(const short8*)(xh + offA + co);
      short8 bhB = *(const short8*)(xh + offB + co);
      short8 blA = *(const short8*)(xl + offA + co);
      short8 blB = *(const short8*)(xl + offB + co);
      bhA = okA ? bhA : zz;  blA = okA ? blA : zz;
      bhB = okB ? bhB : zz;  blB = okB ? blB : zz;
      int kblk = t * 16 + cs * 4 + quad;
      const short* pa = (const short*)Ahi + (size_t)kblk * 256 + n16 * 8;
      const short* pl = (const short*)Alo + (size_t)kblk * 256 + n16 * 8;
      short8 a0 = *(const short8*)pa;
      short8 a1 = *(const short8*)(pa + 128);
      short8 l0 = *(const short8*)pl;
      short8 l1 = *(const short8*)(pl + 128);
      acc[0][0] = __builtin_amdgcn_mfma_f32_16x16x32_bf16(a0, bhA, acc[0][0], 0, 0, 0);
      acc[1][0] = __builtin_amdgcn_mfma_f32_16x16x32_bf16(a1, bhA, acc[1][0], 0, 0, 0);
      acc[0][1] = __builtin_amdgcn_mfma_f32_16x16x32_bf16(a0, bhB, acc[0][1], 0, 0, 0);
      acc[1][1] = __builtin_amdgcn_mfma_f32_16x16x32_bf16(a1, bhB, acc[1][1], 0, 0, 0);
      acc[0][0] = __builtin_amdgcn_mfma_f32_16x16x32_bf16(a0, blA, acc[0][0], 0, 0, 0);
      acc[1][0] = __builtin_amdgcn_mfma_f32_16x16x32_bf16(a1, blA, acc[1][0], 0, 0, 0);
      acc[0][1] = __builtin_amdgcn_mfma_f32_16x16x32_bf16(a0, blB, acc[0][1], 0, 0, 0);
      acc[1][1] = __builtin_amdgcn_mfma_f32_16x16x32_bf16(a1, blB, acc[1][1], 0, 0, 0);
      acc2[0][0] = __builtin_amdgcn_mfma_f32_16x16x32_bf16(l0, bhA, acc2[0][0], 0, 0, 0);
      acc2[1][0] = __builtin_amdgcn_mfma_f32_16x16x32_bf16(l1, bhA, acc2[1][0], 0, 0, 0);
      acc2[0][1] = __builtin_amdgcn_mfma_f32_16x16x32_bf16(l0, bhB, acc2[0][1], 0, 0, 0);
      acc2[1][1] = __builtin_amdgcn_mfma_f32_16x16x32_bf16(l1, bhB, acc2[1][1], 0, 0, 0);
    }
  }
  // epilogue: D row = o = mt*16 + quad*4 + reg; col = pixel = w0 + nf*16 + n16
#pragma unroll
  for (int mt = 0; mt < 2; mt++) {
#pragma unroll
    for (int reg = 0; reg < 4; reg++) {
      int o = mt * 16 + quad * 4 + reg;
      if (o < 27) {
        float bo = b_off[o];
#pragma unroll
        for (int nf = 0; nf < 2; nf++) {
          int w = w0 + nf * 16 + n16;
          om[((size_t)(b * 27 + o) << 14) + (h << 7) + w] =
              acc[mt][nf][reg] + acc2[mt][nf][reg] + bo;
        }
      }
    }
  }
}

// ---------------------------------------------------------------------------
// P3: deformable bilinear sampling + mask + depthwise -> out1[b][h][w][c].
// ---------------------------------------------------------------------------
__global__ __launch_bounds__(256) void k_sample(const float* __restrict__ xn,
                                                const float* __restrict__ om,
                                                const float* __restrict__ w_dw,
                                                const float* __restrict__ b_dw,
                                                float* __restrict__ out1) {
  __shared__ int s_base[4][9], s_dxs[4][9], s_dys[4][9];
  __shared__ float s_w[4][9][4];
  int tid = threadIdx.x;
  int n0 = blockIdx.x * 4;
  if (tid < 36) {
    int pix = tid / 9, k = tid - pix * 9;
    int n = n0 + pix;
    int b = n >> 14, rem = n & 16383;
    int h = rem >> 7, w = rem & 127;
    const float* op = om + b * 27 * HWP + rem;
    float dy = op[(2 * k) * HWP];
    float dx = op[(2 * k + 1) * HWP];
    float mv = op[(18 + k) * HWP];
    mv = 1.0f / (1.0f + __expf(-mv));
    float py = (float)(h + k / 3 - 1) + dy;
    float px = (float)(w + k % 3 - 1) + dx;
    float y0f = floorf(py), x0f = floorf(px);
    float wy = py - y0f, wx = px - x0f;
    int y0 = (int)y0f, x0 = (int)x0f;
    int y1 = y0 + 1, x1 = x0 + 1;
    float v00 = (y0 >= 0 && y0 < HH && x0 >= 0 && x0 < WW) ? 1.f : 0.f;
    float v01 = (y0 >= 0 && y0 < HH && x1 >= 0 && x1 < WW) ? 1.f : 0.f;
    float v10 = (y1 >= 0 && y1 < HH && x0 >= 0 && x0 < WW) ? 1.f : 0.f;
    float v11 = (y1 >= 0 && y1 < HH && x1 >= 0 && x1 < WW) ? 1.f : 0.f;
    int y0c = min(max(y0, 0), HH - 1), y1c = min(max(y1, 0), HH - 1);
    int x0c = min(max(x0, 0), WW - 1), x1c = min(max(x1, 0), WW - 1);
    s_base[pix][k] = ((b * HH + y0c) * WW + x0c) * CC;
    s_dxs[pix][k] = (x1c - x0c) * CC;
    s_dys[pix][k] = (y1c - y0c) * WW * CC;
    s_w[pix][k][0] = (1.f - wy) * (1.f - wx) * mv * v00;
    s_w[pix][k][1] = (1.f - wy) * wx * mv * v01;
    s_w[pix][k][2] = wy * (1.f - wx) * mv * v10;
    s_w[pix][k][3] = wy * wx * mv * v11;
  }
  __syncthreads();
  int wv = tid >> 6, lane = tid & 63;
  int n = n0 + wv;
  int c0 = lane * 2;
  float wka[9], wkb[9];
#pragma unroll
  for (int k = 0; k < 9; k++) {
    wka[k] = w_dw[c0 * 9 + k];
    wkb[k] = w_dw[c0 * 9 + 9 + k];
  }
  float ax = 0.f, ay = 0.f;
#pragma unroll
  for (int k = 0; k < 9; k++) {
    int base = s_base[wv][k] + c0;
    int dxs = s_dxs[wv][k], dys = s_dys[wv][k];
    float4 wgt = *(const float4*)s_w[wv][k];
    float2 v00 = *(const float2*)(xn + base);
    float2 v01 = *(const float2*)(xn + base + dxs);
    float2 v10 = *(const float2*)(xn + base + dys);
    float2 v11 = *(const float2*)(xn + base + dys + dxs);
    float sx = v00.x * wgt.x + v01.x * wgt.y + v10.x * wgt.z + v11.x * wgt.w;
    float sy = v00.y * wgt.x + v01.y * wgt.y + v10.y * wgt.z + v11.y * wgt.w;
    ax = fmaf(sx, wka[k], ax);
    ay = fmaf(sy, wkb[k], ay);
  }
  ax += b_dw[c0];
  ay += b_dw[c0 + 1];
  *(float2*)(out1 + (size_t)n * CC + c0) = make_float2(ax, ay);
}

// ---------------------------------------------------------------------------
// P4: pointwise GEMM fp32 (unchanged this round).
// ---------------------------------------------------------------------------
__global__ __launch_bounds__(256) void k_pw(const float* __restrict__ wpw,
                                            const float* __restrict__ bpw,
                                            const float* __restrict__ bmat,
                                            float* __restrict__ out) {
  __shared__ float As[32][132];
  __shared__ float Bs[32][132];
  int o0 = blockIdx.x * 128;
  int n0 = blockIdx.y * 128;
  int tid = threadIdx.x;
  int to = tid >> 4, tn = tid & 15;
  float acc[8][8] = {};
  for (int kc = 0; kc < 128; kc += 32) {
    __syncthreads();
#pragma unroll
    for (int i = 0; i < 16; i++) {
      int e = i * 256 + tid;
      int oo = e >> 5, kk = e & 31;
      As[kk][oo] = wpw[(o0 + oo) * CC + kc + kk];
    }
#pragma unroll
    for (int i = 0; i < 16; i++) {
      int e = i * 256 + tid;
      int nn = e >> 5, kk = e & 31;
      Bs[kk][nn] = bmat[(size_t)(n0 + nn) * CC + kc + kk];
    }
    __syncthreads();
#pragma unroll
    for (int kk = 0; kk < 32; kk++) {
      float av[8], bv[8];
#pragma unroll
      for (int i = 0; i < 8; i++) av[i] = As[kk][to * 8 + i];
#pragma unroll
      for (int j = 0; j < 8; j++) bv[j] = Bs[kk][tn * 8 + j];
#pragma unroll
      for (int i = 0; i < 8; i++)
#pragma unroll
        for (int j = 0; j < 8; j++) acc[i][j] = fmaf(av[i], bv[j], acc[i][j]);
    }
  }
#pragma unroll
  for (int i = 0; i < 8; i++) {
    int o = o0 + to * 8 + i;
    float bo = bpw[o];
#pragma unroll
    for (int j = 0; j < 8; j++) {
      int n = n0 + tn * 8 + j;
      int b = n >> 14, hw = n & 16383;
      out[((size_t)(b * OO + o) << 14) + hw] = acc[i][j] + bo;
    }
  }
}

// ---------------------------------------------------------------------------
extern "C" void kernel_launch(void* const* d_in, const int* in_sizes, int n_in,
                              void* d_out, int out_size, void* d_ws, size_t ws_size,
                              hipStream_t stream) {
  const float* x     = (const float*)d_in[0];
  const float* w_off = (const float*)d_in[1];
  const float* b_off = (const float*)d_in[2];
  const float* w_dw  = (const float*)d_in[3];
  const float* b_dw  = (const float*)d_in[4];
  const float* w_pw  = (const float*)d_in[5];
  const float* b_pw  = (const float*)d_in[6];
  float* out = (float*)d_out;
  float* ws  = (float*)d_ws;

  // d_out scratch (all dead before k_pw writes):
  //   xn  fp32 NHWC  : out[0 .. 8388608)
  //   xh  bf16 NHWC  : out + 8388608  (4194304 floats worth)
  //   xl  bf16 NHWC  : out + 12582912 (4194304 floats worth) -> exactly 64 MB
  float* xn = out;
  __hip_bfloat16* xh = (__hip_bfloat16*)(out + 8388608);
  __hip_bfloat16* xl = (__hip_bfloat16*)(out + 12582912);

  // ws layout:
  //   om   : ws[0 .. 1769472)
  //   out1 : ws + 1769472 (8388608 floats)
  //   Ahi/Alo live at the START of the out1 region (dead once k_sample writes out1)
  float* om = ws;
  float* out1 = ws + 1769472;
  __hip_bfloat16* Ahi = (__hip_bfloat16*)(ws + 1769472);
  __hip_bfloat16* Alo = Ahi + 36864;

  k_transpose<<<dim3(4, 128, 4), 256, 0, stream>>>(x, xn, xh, xl);
  k_wprep<<<144, 256, 0, stream>>>(w_off, Ahi, Alo);
  k_offconv_mfma<<<dim3(128, 4), 256, 0, stream>>>(xh, xl, Ahi, Alo, b_off, om);
  k_sample<<<16384, 256, 0, stream>>>(xn, om, w_dw, b_dw, out1);
  k_pw<<<dim3(2, 512), 256, 0, stream>>>(w_pw, b_pw, out1, out);
}

// Round 3
// 220.373 us; speedup vs baseline: 2.1677x; 1.4138x over previous
//
#include <hip/hip_runtime.h>
#include <hip/hip_bf16.h>
#include <math.h>

#define BB 4
#define CC 128
#define HH 128
#define WW 128
#define OO 256
#define HWP 16384   // H*W

typedef __attribute__((ext_vector_type(8))) short short8;   // bf16x8 MFMA frag
typedef __attribute__((ext_vector_type(4))) float floatx4;  // MFMA C/D frag

__device__ inline float bf2f(unsigned short u) {
  union { unsigned int i; float f; } z; z.i = ((unsigned)u) << 16; return z.f;
}

// ---------------------------------------------------------------------------
// P1: NCHW -> NHWC bf16 hi/lo split of x (xh for sampling+offconv B, xl for
// offconv correction term). fp32 copy no longer needed.
// ---------------------------------------------------------------------------
__global__ __launch_bounds__(256) void k_transpose(const float* __restrict__ x,
                                                   __hip_bfloat16* __restrict__ xh,
                                                   __hip_bfloat16* __restrict__ xl) {
  __shared__ float tile[64][65];
  int wt = blockIdx.x & 1;
  int ct = blockIdx.x >> 1;
  int h = blockIdx.y, b = blockIdx.z;
  int tw = threadIdx.x & 63;
  int tc = threadIdx.x >> 6;
#pragma unroll
  for (int i = 0; i < 16; i++) {
    int c = ct * 64 + i * 4 + tc;
    tile[i * 4 + tc][tw] = x[((b * CC + c) * HH + h) * WW + wt * 64 + tw];
  }
  __syncthreads();
#pragma unroll
  for (int i = 0; i < 16; i++) {
    int w = wt * 64 + i * 4 + tc;
    int idx = ((b * HH + h) * WW + w) * CC + ct * 64 + tw;
    float v = tile[tw][i * 4 + tc];
    __hip_bfloat16 hv = __float2bfloat16(v);
    xh[idx] = hv;
    xl[idx] = __float2bfloat16(v - __bfloat162float(hv));
  }
}

// ---------------------------------------------------------------------------
// P1b: weight prep. Ahi/Alo: offconv weights [kblk=144][o=32][8] (k=t*128+c).
// Apw: pointwise weights [cblk=16][o=256][8] bf16.
// ---------------------------------------------------------------------------
__global__ __launch_bounds__(256) void k_wprep(const float* __restrict__ w_off,
                                               const float* __restrict__ w_pw,
                                               __hip_bfloat16* __restrict__ Ahi,
                                               __hip_bfloat16* __restrict__ Alo,
                                               __hip_bfloat16* __restrict__ Apw) {
  int e = blockIdx.x * 256 + threadIdx.x;
  if (e < 144 * 32 * 8) {
    int kblk = e >> 8;
    int o = (e >> 3) & 31;
    int j = e & 7;
    int k = kblk * 8 + j;
    int t = k >> 7, c = k & 127;
    float w = (o < 27) ? w_off[(o * CC + c) * 9 + t] : 0.0f;
    __hip_bfloat16 hv = __float2bfloat16(w);
    Ahi[e] = hv;
    Alo[e] = __float2bfloat16(w - __bfloat162float(hv));
  }
  int e2 = e - 144 * 32 * 8;
  if (e2 >= 0 && e2 < 16 * 256 * 8) {
    int cblk = e2 >> 11;
    int o = (e2 >> 3) & 255;
    int j = e2 & 7;
    Apw[e2] = __float2bfloat16(w_pw[o * CC + cblk * 8 + j]);
  }
}

// ---------------------------------------------------------------------------
// P2: offset conv as MFMA implicit GEMM (hi/lo split, drops lo.lo only).
// 1D grid 512, XCD-swizzled: xcd=bid&7 -> 16-row band of one image.
// ---------------------------------------------------------------------------
__global__ __launch_bounds__(256) void k_offconv_mfma(
    const __hip_bfloat16* __restrict__ xh, const __hip_bfloat16* __restrict__ xl,
    const __hip_bfloat16* __restrict__ Ahi, const __hip_bfloat16* __restrict__ Alo,
    const float* __restrict__ b_off, float* __restrict__ om) {
  int bid = blockIdx.x;
  int xcd = bid & 7, r = bid >> 3;
  int b = r >> 4;
  int h = xcd * 16 + (r & 15);
  int tid = threadIdx.x;
  int wv = tid >> 6, lane = tid & 63;
  int w0 = wv * 32;
  int n16 = lane & 15, quad = lane >> 4;

  floatx4 acc[2][2] = {};
  floatx4 acc2[2][2] = {};
  short8 zz = {};

  for (int t = 0; t < 9; t++) {
    int dy = t / 3 - 1, dx = t % 3 - 1;
    int hs = h + dy;
    bool hok = ((unsigned)hs < HH);
    int hsc = min(max(hs, 0), HH - 1);
    int wA = w0 + n16 + dx;
    int wB = wA + 16;
    bool okA = hok && ((unsigned)wA < WW);
    bool okB = hok && ((unsigned)wB < WW);
    int wAc = min(max(wA, 0), WW - 1);
    int wBc = min(max(wB, 0), WW - 1);
    size_t offA = (size_t)((b * HH + hsc) * WW + wAc) * CC + quad * 8;
    size_t offB = (size_t)((b * HH + hsc) * WW + wBc) * CC + quad * 8;
#pragma unroll
    for (int cs = 0; cs < 4; cs++) {
      int co = cs * 32;
      short8 bhA = *(const short8*)(xh + offA + co);
      short8 bhB = *(const short8*)(xh + offB + co);
      short8 blA = *(const short8*)(xl + offA + co);
      short8 blB = *(const short8*)(xl + offB + co);
      bhA = okA ? bhA : zz;  blA = okA ? blA : zz;
      bhB = okB ? bhB : zz;  blB = okB ? blB : zz;
      int kblk = t * 16 + cs * 4 + quad;
      const short* pa = (const short*)Ahi + (size_t)kblk * 256 + n16 * 8;
      const short* pl = (const short*)Alo + (size_t)kblk * 256 + n16 * 8;
      short8 a0 = *(const short8*)pa;
      short8 a1 = *(const short8*)(pa + 128);
      short8 l0 = *(const short8*)pl;
      short8 l1 = *(const short8*)(pl + 128);
      acc[0][0] = __builtin_amdgcn_mfma_f32_16x16x32_bf16(a0, bhA, acc[0][0], 0, 0, 0);
      acc[1][0] = __builtin_amdgcn_mfma_f32_16x16x32_bf16(a1, bhA, acc[1][0], 0, 0, 0);
      acc[0][1] = __builtin_amdgcn_mfma_f32_16x16x32_bf16(a0, bhB, acc[0][1], 0, 0, 0);
      acc[1][1] = __builtin_amdgcn_mfma_f32_16x16x32_bf16(a1, bhB, acc[1][1], 0, 0, 0);
      acc[0][0] = __builtin_amdgcn_mfma_f32_16x16x32_bf16(a0, blA, acc[0][0], 0, 0, 0);
      acc[1][0] = __builtin_amdgcn_mfma_f32_16x16x32_bf16(a1, blA, acc[1][0], 0, 0, 0);
      acc[0][1] = __builtin_amdgcn_mfma_f32_16x16x32_bf16(a0, blB, acc[0][1], 0, 0, 0);
      acc[1][1] = __builtin_amdgcn_mfma_f32_16x16x32_bf16(a1, blB, acc[1][1], 0, 0, 0);
      acc2[0][0] = __builtin_amdgcn_mfma_f32_16x16x32_bf16(l0, bhA, acc2[0][0], 0, 0, 0);
      acc2[1][0] = __builtin_amdgcn_mfma_f32_16x16x32_bf16(l1, bhA, acc2[1][0], 0, 0, 0);
      acc2[0][1] = __builtin_amdgcn_mfma_f32_16x16x32_bf16(l0, bhB, acc2[0][1], 0, 0, 0);
      acc2[1][1] = __builtin_amdgcn_mfma_f32_16x16x32_bf16(l1, bhB, acc2[1][1], 0, 0, 0);
    }
  }
#pragma unroll
  for (int mt = 0; mt < 2; mt++) {
#pragma unroll
    for (int reg = 0; reg < 4; reg++) {
      int o = mt * 16 + quad * 4 + reg;
      if (o < 27) {
        float bo = b_off[o];
#pragma unroll
        for (int nf = 0; nf < 2; nf++) {
          int w = w0 + nf * 16 + n16;
          om[((size_t)(b * 27 + o) << 14) + (h << 7) + w] =
              acc[mt][nf][reg] + acc2[mt][nf][reg] + bo;
        }
      }
    }
  }
}

// ---------------------------------------------------------------------------
// P3: deformable sampling + mask + depthwise, gathering bf16 xh.
// Block = 8 pixels (4 waves, 2 px/wave, 32 lanes x 4ch). XCD-swizzled so each
// XCD covers a contiguous 8192-pixel band (~2 MB xh footprint -> L2-resident).
// Emits out1 as bf16 [n][c].
// ---------------------------------------------------------------------------
__global__ __launch_bounds__(256) void k_sample(const unsigned short* __restrict__ xh,
                                                const float* __restrict__ om,
                                                const float* __restrict__ w_dw,
                                                const float* __restrict__ b_dw,
                                                unsigned short* __restrict__ out1b) {
  __shared__ int s_base[8][9], s_dxs[8][9], s_dys[8][9];
  __shared__ float s_w[8][9][4];
  int tid = threadIdx.x;
  int bid = blockIdx.x;
  int n0 = ((bid & 7) * 1024 + (bid >> 3)) * 8;   // XCD-contiguous bands
  if (tid < 72) {
    int pix = tid / 9, k = tid - pix * 9;
    int n = n0 + pix;
    int b = n >> 14, rem = n & 16383;
    int h = rem >> 7, w = rem & 127;
    const float* op = om + b * 27 * HWP + rem;
    float dy = op[(2 * k) * HWP];
    float dx = op[(2 * k + 1) * HWP];
    float mv = op[(18 + k) * HWP];
    mv = 1.0f / (1.0f + __expf(-mv));
    float py = (float)(h + k / 3 - 1) + dy;
    float px = (float)(w + k % 3 - 1) + dx;
    float y0f = floorf(py), x0f = floorf(px);
    float wy = py - y0f, wx = px - x0f;
    int y0 = (int)y0f, x0 = (int)x0f;
    int y1 = y0 + 1, x1 = x0 + 1;
    float v00 = (y0 >= 0 && y0 < HH && x0 >= 0 && x0 < WW) ? 1.f : 0.f;
    float v01 = (y0 >= 0 && y0 < HH && x1 >= 0 && x1 < WW) ? 1.f : 0.f;
    float v10 = (y1 >= 0 && y1 < HH && x0 >= 0 && x0 < WW) ? 1.f : 0.f;
    float v11 = (y1 >= 0 && y1 < HH && x1 >= 0 && x1 < WW) ? 1.f : 0.f;
    int y0c = min(max(y0, 0), HH - 1), y1c = min(max(y1, 0), HH - 1);
    int x0c = min(max(x0, 0), WW - 1), x1c = min(max(x1, 0), WW - 1);
    s_base[pix][k] = ((b * HH + y0c) * WW + x0c) * CC;
    s_dxs[pix][k] = (x1c - x0c) * CC;
    s_dys[pix][k] = (y1c - y0c) * WW * CC;
    s_w[pix][k][0] = (1.f - wy) * (1.f - wx) * mv * v00;
    s_w[pix][k][1] = (1.f - wy) * wx * mv * v01;
    s_w[pix][k][2] = wy * (1.f - wx) * mv * v10;
    s_w[pix][k][3] = wy * wx * mv * v11;
  }
  __syncthreads();
  int wv = tid >> 6, lane = tid & 63;
  int pix = wv * 2 + (lane >> 5);
  int cl = lane & 31;
  int c0 = cl * 4;
  int n = n0 + pix;
  // depthwise weights for channels c0..c0+3: 36 contiguous floats
  float4 wk4[9];
#pragma unroll
  for (int i = 0; i < 9; i++) wk4[i] = *(const float4*)(w_dw + c0 * 9 + i * 4);
  const float* wkf = (const float*)wk4;   // wkf[j*9 + k]
  float acc0 = 0.f, acc1 = 0.f, acc2v = 0.f, acc3 = 0.f;
#pragma unroll
  for (int k = 0; k < 9; k++) {
    int base = s_base[pix][k] + c0;
    int dxs = s_dxs[pix][k], dys = s_dys[pix][k];
    float4 wgt = *(const float4*)s_w[pix][k];
    ushort4 v00 = *(const ushort4*)(xh + base);
    ushort4 v01 = *(const ushort4*)(xh + base + dxs);
    ushort4 v10 = *(const ushort4*)(xh + base + dys);
    ushort4 v11 = *(const ushort4*)(xh + base + dys + dxs);
    float s0 = wgt.x * bf2f(v00.x) + wgt.y * bf2f(v01.x) + wgt.z * bf2f(v10.x) + wgt.w * bf2f(v11.x);
    float s1 = wgt.x * bf2f(v00.y) + wgt.y * bf2f(v01.y) + wgt.z * bf2f(v10.y) + wgt.w * bf2f(v11.y);
    float s2 = wgt.x * bf2f(v00.z) + wgt.y * bf2f(v01.z) + wgt.z * bf2f(v10.z) + wgt.w * bf2f(v11.z);
    float s3 = wgt.x * bf2f(v00.w) + wgt.y * bf2f(v01.w) + wgt.z * bf2f(v10.w) + wgt.w * bf2f(v11.w);
    acc0 = fmaf(s0, wkf[0 * 9 + k], acc0);
    acc1 = fmaf(s1, wkf[1 * 9 + k], acc1);
    acc2v = fmaf(s2, wkf[2 * 9 + k], acc2v);
    acc3 = fmaf(s3, wkf[3 * 9 + k], acc3);
  }
  float4 bd = *(const float4*)(b_dw + c0);
  acc0 += bd.x; acc1 += bd.y; acc2v += bd.z; acc3 += bd.w;
  ushort4 ov;
  ov.x = __bfloat16_as_ushort(__float2bfloat16(acc0));
  ov.y = __bfloat16_as_ushort(__float2bfloat16(acc1));
  ov.z = __bfloat16_as_ushort(__float2bfloat16(acc2v));
  ov.w = __bfloat16_as_ushort(__float2bfloat16(acc3));
  *(ushort4*)(out1b + (size_t)n * CC + c0) = ov;
}

// ---------------------------------------------------------------------------
// P4: pointwise GEMM, bf16 MFMA. Block = 4 waves; block tile 256o x 64n.
// Wave wv: o in [wv*64, wv*64+64), all 64 n. Grid 1024, XCD-swizzled.
// ---------------------------------------------------------------------------
__global__ __launch_bounds__(256) void k_pw_mfma(const __hip_bfloat16* __restrict__ Apw,
                                                 const unsigned short* __restrict__ out1b,
                                                 const float* __restrict__ bpw,
                                                 float* __restrict__ out) {
  int bid = blockIdx.x;
  int n0 = ((bid & 7) * 128 + (bid >> 3)) * 64;
  int tid = threadIdx.x;
  int wv = tid >> 6, lane = tid & 63;
  int n16 = lane & 15, quad = lane >> 4;
  int obase = wv * 64;

  floatx4 acc[4][4] = {};   // [mf][nf]
#pragma unroll
  for (int cs = 0; cs < 4; cs++) {
    short8 af[4], bf[4];
#pragma unroll
    for (int mf = 0; mf < 4; mf++) {
      const short* pa = (const short*)Apw + ((size_t)(cs * 4 + quad) * 256 + obase + mf * 16 + n16) * 8;
      af[mf] = *(const short8*)pa;
    }
#pragma unroll
    for (int nf = 0; nf < 4; nf++) {
      const short* pb = (const short*)out1b + (size_t)(n0 + nf * 16 + n16) * CC + cs * 32 + quad * 8;
      bf[nf] = *(const short8*)pb;
    }
#pragma unroll
    for (int mf = 0; mf < 4; mf++)
#pragma unroll
      for (int nf = 0; nf < 4; nf++)
        acc[mf][nf] = __builtin_amdgcn_mfma_f32_16x16x32_bf16(af[mf], bf[nf], acc[mf][nf], 0, 0, 0);
  }
  int b = n0 >> 14;
#pragma unroll
  for (int mf = 0; mf < 4; mf++) {
#pragma unroll
    for (int reg = 0; reg < 4; reg++) {
      int o = obase + mf * 16 + quad * 4 + reg;
      float bo = bpw[o];
#pragma unroll
      for (int nf = 0; nf < 4; nf++) {
        int n = n0 + nf * 16 + n16;
        int hw = n & 16383;
        out[((size_t)(b * OO + o) << 14) + hw] = acc[mf][nf][reg] + bo;
      }
    }
  }
}

// ---------------------------------------------------------------------------
extern "C" void kernel_launch(void* const* d_in, const int* in_sizes, int n_in,
                              void* d_out, int out_size, void* d_ws, size_t ws_size,
                              hipStream_t stream) {
  const float* x     = (const float*)d_in[0];
  const float* w_off = (const float*)d_in[1];
  const float* b_off = (const float*)d_in[2];
  const float* w_dw  = (const float*)d_in[3];
  const float* b_dw  = (const float*)d_in[4];
  const float* w_pw  = (const float*)d_in[5];
  const float* b_pw  = (const float*)d_in[6];
  float* out = (float*)d_out;
  float* ws  = (float*)d_ws;

  // d_out scratch (dead before k_pw_mfma writes): xh, xl bf16 NHWC
  __hip_bfloat16* xh = (__hip_bfloat16*)out;
  __hip_bfloat16* xl = xh + 8388608;

  // ws: om fp32 | out1b bf16 | Ahi | Alo | Apw
  float* om = ws;                                           // 1769472 floats
  unsigned short* out1b = (unsigned short*)(ws + 1769472);  // 8388608 bf16
  __hip_bfloat16* Ahi = (__hip_bfloat16*)(ws + 5963776);    // 36864
  __hip_bfloat16* Alo = Ahi + 36864;                        // 36864
  __hip_bfloat16* Apw = Alo + 36864;                        // 32768

  k_transpose<<<dim3(4, 128, 4), 256, 0, stream>>>(x, xh, xl);
  k_wprep<<<416, 256, 0, stream>>>(w_off, w_pw, Ahi, Alo, Apw);
  k_offconv_mfma<<<512, 256, 0, stream>>>(xh, xl, Ahi, Alo, b_off, om);
  k_sample<<<8192, 256, 0, stream>>>((const unsigned short*)xh, om, w_dw, b_dw, out1b);
  k_pw_mfma<<<1024, 256, 0, stream>>>(Apw, out1b, b_pw, out);
}